// Round 2
// baseline (387.960 us; speedup 1.0000x reference)
//
#include <hip/hip_runtime.h>
#include <cstddef>

// Problem constants (match reference): B=32, D=64, T=8192, K=512
#define B_ 32
#define D_ 64
#define T_ 8192
#define K_ 512

typedef float v2f __attribute__((ext_vector_type(2)));

// ---------------------------------------------------------------------------
// One thread per (b,t). Bit-replicates the numpy fp32 pipeline:
//   x2  = np.sum(xp*xp, -1)        -> pairwise 8-accumulator block (n=64)
//   e2  = np.sum(emb*emb, -1)      -> same pairwise scheme (precomputed in LDS)
//   xe  = np.einsum('btd,kd->btk') -> npyv AVX512 dot: 16 lanes, 4-deep fused
//                                     FMA chain + 8/4/2/1 pairwise reduce
//   dist = (x2 - 2*xe) + e2        -> two fp32 roundings (2*xe is exact)
//   argmin: strict <, first index wins (np.argmin tie-break)
// ---------------------------------------------------------------------------
__global__ __launch_bounds__(256) void vq_kernel(const float* __restrict__ x,
                                                 const float* __restrict__ emb,
                                                 float* __restrict__ out) {
    __shared__ float s_e2[K_];

    // ---- e2 precompute into LDS, numpy pairwise-8 order, no FMA contraction
    {
#pragma clang fp contract(off)
        for (int k = threadIdx.x; k < K_; k += 256) {
            const float* er = emb + k * D_;
            float r[8];
#pragma unroll
            for (int j = 0; j < 8; ++j) r[j] = er[j] * er[j];
#pragma unroll
            for (int i = 8; i < 64; i += 8) {
#pragma unroll
                for (int j = 0; j < 8; ++j) {
                    float p = er[i + j] * er[i + j];
                    r[j] = r[j] + p;
                }
            }
            s_e2[k] = ((r[0] + r[1]) + (r[2] + r[3])) + ((r[4] + r[5]) + (r[6] + r[7]));
        }
    }
    __syncthreads();

    const int t = blockIdx.x * 256 + threadIdx.x;
    const int b = blockIdx.y;
    const float* xp = x + ((size_t)b * D_) * T_ + t;

    // ---- load x[b, :, t] (coalesced across lanes: consecutive t)
    float xr[D_];
#pragma unroll
    for (int d = 0; d < D_; ++d) xr[d] = xp[(size_t)d * T_];

    // ---- x2 via numpy pairwise-8 (products first, then sequential adds)
    float x2;
    {
#pragma clang fp contract(off)
        float r[8];
#pragma unroll
        for (int j = 0; j < 8; ++j) r[j] = xr[j] * xr[j];
#pragma unroll
        for (int i = 8; i < 64; i += 8) {
#pragma unroll
            for (int j = 0; j < 8; ++j) {
                float p = xr[i + j] * xr[i + j];
                r[j] = r[j] + p;
            }
        }
        x2 = ((r[0] + r[1]) + (r[2] + r[3])) + ((r[4] + r[5]) + (r[6] + r[7]));
    }

    // ---- K-loop: replicate einsum npyv dot (AVX512: vstep=16, one x4 iter)
    float best = 3.4e38f;
    int bi = 0;
    {
#pragma clang fp contract(off)
        for (int k = 0; k < K_; ++k) {
            const float* er = emb + k * D_;  // wave-uniform -> scalar loads

            // acc[j] holds SIMD lanes (2j, 2j+1); lane L accumulates d in
            // {L, L+16, L+32, L+48} via the chained muladd:
            //   acc = fma(a0,b0, fma(a1,b1, fma(a2,b2, fma(a3,b3, 0))))
            v2f acc[8];
#pragma unroll
            for (int j = 0; j < 8; ++j) {
                int L = 2 * j;
                v2f xv, ev, z;
                z[0] = 0.f; z[1] = 0.f;
                // a3*b3 + 0  (d = 48+L, 49+L)
                xv[0] = xr[48 + L]; xv[1] = xr[49 + L];
                ev[0] = er[48 + L]; ev[1] = er[49 + L];
                acc[j] = __builtin_elementwise_fma(xv, ev, z);
                // a2*b2 + .  (d = 32+L)
                xv[0] = xr[32 + L]; xv[1] = xr[33 + L];
                ev[0] = er[32 + L]; ev[1] = er[33 + L];
                acc[j] = __builtin_elementwise_fma(xv, ev, acc[j]);
                // a1*b1 + .  (d = 16+L)
                xv[0] = xr[16 + L]; xv[1] = xr[17 + L];
                ev[0] = er[16 + L]; ev[1] = er[17 + L];
                acc[j] = __builtin_elementwise_fma(xv, ev, acc[j]);
                // a0*b0 + .  (d = L)
                xv[0] = xr[0 + L];  xv[1] = xr[1 + L];
                ev[0] = er[0 + L];  ev[1] = er[1 + L];
                acc[j] = __builtin_elementwise_fma(xv, ev, acc[j]);
            }

            // _mm512_reduce_add_ps tree: strides 8, 4, 2, 1 (pairwise)
            v2f s8_0 = acc[0] + acc[4];  // lanes (0,1)+(8,9)
            v2f s8_1 = acc[1] + acc[5];  // lanes (2,3)+(10,11)
            v2f s8_2 = acc[2] + acc[6];  // lanes (4,5)+(12,13)
            v2f s8_3 = acc[3] + acc[7];  // lanes (6,7)+(14,15)
            v2f s4_0 = s8_0 + s8_2;      // u: (0,1)+(4,5)
            v2f s4_1 = s8_1 + s8_3;      // u: (2,3)+(6,7)
            v2f s2   = s4_0 + s4_1;      // v: (0,1)+(2,3)
            float xe = s2[0] + s2[1];    // w0 + w1

            float h    = 2.0f * xe;      // exact (power of two)
            float tt   = x2 - h;         // one rounding
            float dist = tt + s_e2[k];   // one rounding

            if (dist < best) { best = dist; bi = k; }  // strict: first index wins
        }
    }

    // ---- epilogue: out0 = x + (q - x) elementwise fp32 (mirrors reference),
    //      out1 = q (exact gather). Coalesced stores.
    const float* q = emb + bi * D_;
    float* o0 = out + ((size_t)b * D_) * T_ + t;
    float* o1 = o0 + (size_t)B_ * D_ * T_;
    {
#pragma clang fp contract(off)
#pragma unroll
        for (int d = 0; d < D_; ++d) {
            float qd = q[d];
            float xd = xr[d];
            float diff = qd - xd;
            o0[(size_t)d * T_] = xd + diff;
            o1[(size_t)d * T_] = qd;
        }
    }
}

extern "C" void kernel_launch(void* const* d_in, const int* in_sizes, int n_in,
                              void* d_out, int out_size, void* d_ws, size_t ws_size,
                              hipStream_t stream) {
    const float* x   = (const float*)d_in[0];   // [B, D, T] fp32
    const float* emb = (const float*)d_in[1];   // [K, D] fp32
    float* out = (float*)d_out;                 // [2, B, D, T] fp32

    vq_kernel<<<dim3(T_ / 256, B_), dim3(256), 0, stream>>>(x, emb, out);
}

// Round 3
// 370.989 us; speedup vs baseline: 1.0457x; 1.0457x over previous
//
#include <hip/hip_runtime.h>
#include <cstddef>

// Problem constants (match reference): B=32, D=64, T=8192, K=512
#define B_ 32
#define D_ 64
#define T_ 8192
#define K_ 512

typedef float v2f __attribute__((ext_vector_type(2)));

// ---------------------------------------------------------------------------
// One thread per (b,t). Bit-replicates the numpy fp32 pipeline (verified
// absmax==0 in round 2):
//   x2  = np.sum(xp*xp, -1)        -> pairwise 8-accumulator block (n=64)
//   e2  = np.sum(emb*emb, -1)      -> same pairwise scheme (precomputed in LDS)
//   xe  = np.einsum('btd,kd->btk') -> npyv AVX512 dot: 16 lanes, 4-deep fused
//                                     FMA chain + 8/4/2/1 pairwise reduce
//   dist = fma(-2, xe, x2) + e2    -> identical to (x2 - 2*xe) + e2 since
//                                     2*xe is exact and fma rounds once
//   argmin: strict <, first index wins (np.argmin tie-break)
//
// __launch_bounds__(256, 4): cap at 4 waves/EU -> 128 VGPR budget so the
// 64-float x column stays RESIDENT in VGPRs (round-2 build squeezed to
// 48 VGPRs for unusable occupancy and re-fetched x inside the K loop).
// Grid supplies only 4 waves/SIMD, so 4 waves/EU costs nothing.
// ---------------------------------------------------------------------------
__global__ __launch_bounds__(256, 4) void vq_kernel(const float* __restrict__ x,
                                                    const float* __restrict__ emb,
                                                    float* __restrict__ out) {
    __shared__ float s_e2[K_];

    // ---- e2 precompute into LDS, numpy pairwise-8 order, no FMA contraction
    {
#pragma clang fp contract(off)
        for (int k = threadIdx.x; k < K_; k += 256) {
            const float* er = emb + k * D_;
            float r[8];
#pragma unroll
            for (int j = 0; j < 8; ++j) r[j] = er[j] * er[j];
#pragma unroll
            for (int i = 8; i < 64; i += 8) {
#pragma unroll
                for (int j = 0; j < 8; ++j) {
                    float p = er[i + j] * er[i + j];
                    r[j] = r[j] + p;
                }
            }
            s_e2[k] = ((r[0] + r[1]) + (r[2] + r[3])) + ((r[4] + r[5]) + (r[6] + r[7]));
        }
    }
    __syncthreads();

    const int t = blockIdx.x * 256 + threadIdx.x;
    const int b = blockIdx.y;
    const float* xp = x + ((size_t)b * D_) * T_ + t;

    // ---- load x[b, :, t] into 32 packed v2f regs (coalesced across lanes)
    v2f xr[D_ / 2];
#pragma unroll
    for (int j = 0; j < D_ / 2; ++j) {
        v2f p;
        p[0] = xp[(size_t)(2 * j) * T_];
        p[1] = xp[(size_t)(2 * j + 1) * T_];
        xr[j] = p;
    }
#define XD(d) (xr[(d) >> 1][(d) & 1])

    // ---- x2 via numpy pairwise-8 (products first, then sequential adds)
    float x2;
    {
#pragma clang fp contract(off)
        float r[8];
#pragma unroll
        for (int j = 0; j < 8; ++j) r[j] = XD(j) * XD(j);
#pragma unroll
        for (int i = 8; i < 64; i += 8) {
#pragma unroll
            for (int j = 0; j < 8; ++j) {
                float p = XD(i + j) * XD(i + j);
                r[j] = r[j] + p;
            }
        }
        x2 = ((r[0] + r[1]) + (r[2] + r[3])) + ((r[4] + r[5]) + (r[6] + r[7]));
    }

    // ---- K-loop: replicate einsum npyv dot (AVX512: vstep=16, one x4 iter)
    float best = 3.4e38f;
    int bi = 0;
    {
#pragma clang fp contract(off)
        for (int k = 0; k < K_; ++k) {
            const float* er = emb + k * D_;  // wave-uniform -> scalar loads

            // acc[j] holds SIMD lanes (2j, 2j+1); lane L accumulates d in
            // {L, L+16, L+32, L+48}: acc = fma(a0,b0, fma(a1,b1, fma(a2,b2, fma(a3,b3, 0))))
            v2f acc[8];
#pragma unroll
            for (int j = 0; j < 8; ++j) {
                int L = 2 * j;
                v2f ev, z;
                z[0] = 0.f; z[1] = 0.f;
                ev[0] = er[48 + L]; ev[1] = er[49 + L];
                acc[j] = __builtin_elementwise_fma(xr[(48 + L) >> 1], ev, z);
                ev[0] = er[32 + L]; ev[1] = er[33 + L];
                acc[j] = __builtin_elementwise_fma(xr[(32 + L) >> 1], ev, acc[j]);
                ev[0] = er[16 + L]; ev[1] = er[17 + L];
                acc[j] = __builtin_elementwise_fma(xr[(16 + L) >> 1], ev, acc[j]);
                ev[0] = er[0 + L];  ev[1] = er[1 + L];
                acc[j] = __builtin_elementwise_fma(xr[(0 + L) >> 1], ev, acc[j]);
            }

            // _mm512_reduce_add_ps tree: strides 8, 4, 2, 1 (pairwise)
            v2f s8_0 = acc[0] + acc[4];
            v2f s8_1 = acc[1] + acc[5];
            v2f s8_2 = acc[2] + acc[6];
            v2f s8_3 = acc[3] + acc[7];
            v2f s4_0 = s8_0 + s8_2;
            v2f s4_1 = s8_1 + s8_3;
            v2f s2   = s4_0 + s4_1;
            float xe = s2[0] + s2[1];

            // fl(x2 - 2*xe) via fma: 2*xe exact, single rounding -> identical
            float tt   = fmaf(-2.0f, xe, x2);
            float dist = tt + s_e2[k];

            if (dist < best) { best = dist; bi = k; }  // strict: first index wins
        }
    }

    // ---- epilogue: out0 = x + (q - x) elementwise fp32, out1 = q
    const float* q = emb + bi * D_;
    float* o0 = out + ((size_t)b * D_) * T_ + t;
    float* o1 = o0 + (size_t)B_ * D_ * T_;
    {
#pragma clang fp contract(off)
#pragma unroll
        for (int d = 0; d < D_; ++d) {
            float qd = q[d];
            float xd = XD(d);
            float diff = qd - xd;
            o0[(size_t)d * T_] = xd + diff;
            o1[(size_t)d * T_] = qd;
        }
    }
#undef XD
}

extern "C" void kernel_launch(void* const* d_in, const int* in_sizes, int n_in,
                              void* d_out, int out_size, void* d_ws, size_t ws_size,
                              hipStream_t stream) {
    const float* x   = (const float*)d_in[0];   // [B, D, T] fp32
    const float* emb = (const float*)d_in[1];   // [K, D] fp32
    float* out = (float*)d_out;                 // [2, B, D, T] fp32

    vq_kernel<<<dim3(T_ / 256, B_), dim3(256), 0, stream>>>(x, emb, out);
}